// Round 8
// baseline (688.123 us; speedup 1.0000x reference)
//
#include <hip/hip_runtime.h>
#include <math.h>

#define N_PTS  8192
#define BATCH  2
#define NSETS  4                 // s = b*2 + t ; t=0: pc2, t=1: warped pc1
#define G      16
#define CELLS  (G * G * G)       // 4096
#define BOXLO  (-6.5f)
#define CELLH  0.8125f           // 13/16
#define INVH   (1.0f / CELLH)
#define TOTQ   (2 * BATCH * N_PTS)   // 32768 queries
#define RBLK   (TOTQ / 256)          // 128 reduce blocks

// ws layout (all rewritten every call; poison-safe):
//   pts    float4[NSETS*N_PTS]  raw points, .w = cell-id bits        (512 KB)
//   sorted float4[NSETS*N_PTS]  cell-sorted points                   (512 KB)
//   cnt    uint[NSETS*CELLS]                                          (64 KB)
//   start  uint[NSETS*CELLS]    exclusive scan of cnt                 (64 KB)
//   cursor uint[NSETS*CELLS]    scatter cursors (init = start)        (64 KB)
//   nnd2   float[TOTQ]          per-query min d^2                    (128 KB)
//   accum  float, counter uint

__device__ __forceinline__ int cell_of(float x, float y, float z) {
    int cx = (int)floorf((x - BOXLO) * INVH);
    int cy = (int)floorf((y - BOXLO) * INVH);
    int cz = (int)floorf((z - BOXLO) * INVH);
    cx = min(max(cx, 0), G - 1);
    cy = min(max(cy, 0), G - 1);
    cz = min(max(cz, 0), G - 1);
    return (cz * G + cy) * G + cx;
}

__global__ __launch_bounds__(256) void grid_zero(unsigned int* __restrict__ cnt,
                                                 float* __restrict__ accum,
                                                 unsigned int* __restrict__ counter) {
    int i = blockIdx.x * 256 + threadIdx.x;
    if (i < NSETS * CELLS) cnt[i] = 0u;
    if (i == 0) { *accum = 0.0f; *counter = 0u; }
}

__global__ __launch_bounds__(256) void grid_prep(const float* __restrict__ pc1,
                                                 const float* __restrict__ pc2,
                                                 const float* __restrict__ flow,
                                                 float4* __restrict__ pts,
                                                 unsigned int* __restrict__ cnt) {
    int i = blockIdx.x * 256 + threadIdx.x;      // 0 .. BATCH*N_PTS-1
    if (i >= BATCH * N_PTS) return;
    int b = i >> 13, j = i & (N_PTS - 1);

    float px = pc2[i * 3 + 0], py = pc2[i * 3 + 1], pz = pc2[i * 3 + 2];
    int c0 = cell_of(px, py, pz);
    pts[(size_t)(b * 2 + 0) * N_PTS + j] =
        make_float4(px, py, pz, __uint_as_float((unsigned)c0));
    atomicAdd(&cnt[(b * 2 + 0) * CELLS + c0], 1u);

    float wx = pc1[i * 3 + 0] + flow[i * 3 + 0];
    float wy = pc1[i * 3 + 1] + flow[i * 3 + 1];
    float wz = pc1[i * 3 + 2] + flow[i * 3 + 2];
    int c1 = cell_of(wx, wy, wz);
    pts[(size_t)(b * 2 + 1) * N_PTS + j] =
        make_float4(wx, wy, wz, __uint_as_float((unsigned)c1));
    atomicAdd(&cnt[(b * 2 + 1) * CELLS + c1], 1u);
}

// One block per set: exclusive scan of 4096 counts (4 per thread, 1024 thr).
__global__ __launch_bounds__(1024) void grid_scan(const unsigned int* __restrict__ cnt,
                                                  unsigned int* __restrict__ start,
                                                  unsigned int* __restrict__ cursor) {
    __shared__ unsigned int tsum[1024];
    const int s   = blockIdx.x;
    const int tid = threadIdx.x;
    const unsigned int* c = cnt + (size_t)s * CELLS;

    unsigned int v0 = c[tid * 4 + 0], v1 = c[tid * 4 + 1];
    unsigned int v2 = c[tid * 4 + 2], v3 = c[tid * 4 + 3];
    tsum[tid] = v0 + v1 + v2 + v3;
    __syncthreads();
    // Hillis-Steele inclusive scan over 1024 partials
    for (int off = 1; off < 1024; off <<= 1) {
        unsigned int add = (tid >= off) ? tsum[tid - off] : 0u;
        __syncthreads();
        tsum[tid] += add;
        __syncthreads();
    }
    unsigned int base = (tid == 0) ? 0u : tsum[tid - 1];
    unsigned int o0 = base, o1 = o0 + v0, o2 = o1 + v1, o3 = o2 + v2;
    size_t off = (size_t)s * CELLS + tid * 4;
    start[off + 0] = o0; start[off + 1] = o1;
    start[off + 2] = o2; start[off + 3] = o3;
    cursor[off + 0] = o0; cursor[off + 1] = o1;
    cursor[off + 2] = o2; cursor[off + 3] = o3;
}

__global__ __launch_bounds__(256) void grid_scatter(const float4* __restrict__ pts,
                                                    unsigned int* __restrict__ cursor,
                                                    float4* __restrict__ sorted) {
    int i = blockIdx.x * 256 + threadIdx.x;      // 0 .. NSETS*N_PTS-1
    if (i >= NSETS * N_PTS) return;
    int s = i >> 13;
    float4 p = pts[i];
    unsigned int cell = __float_as_uint(p.w);
    unsigned int pos  = atomicAdd(&cursor[s * CELLS + cell], 1u);
    sorted[(size_t)s * N_PTS + pos] = p;
}

// Exact 1-NN via expanding Chebyshev shells. Stop rule: after completing
// shell r, every unsearched cell is Chebyshev >= r+1 away, and since the
// cell clamp is 1-Lipschitz, any point there is >= r*CELLH away. Exact.
__global__ __launch_bounds__(64) void grid_query(const float4* __restrict__ pts,
                                                 const unsigned int* __restrict__ cnt,
                                                 const unsigned int* __restrict__ start,
                                                 const float4* __restrict__ sorted,
                                                 float* __restrict__ nnd2) {
    const int q   = blockIdx.x * 64 + threadIdx.x;   // < TOTQ
    const int dir = q >> 14;                         // 0 or 1
    const int rem = q & 16383;
    const int b   = rem >> 13;
    const int i   = rem & (N_PTS - 1);
    const int tq  = (dir == 0) ? 1 : 0;              // query set type
    const int sq  = b * 2 + tq;
    const int sd  = b * 2 + (1 - tq);                // DB set

    const float4 p = pts[(size_t)sq * N_PTS + i];
    const float qx = p.x, qy = p.y, qz = p.z;
    const unsigned int qcell = __float_as_uint(p.w);
    const int cx = qcell & (G - 1);
    const int cy = (qcell >> 4) & (G - 1);
    const int cz = qcell >> 8;

    const unsigned int* __restrict__ cs = cnt   + (size_t)sd * CELLS;
    const unsigned int* __restrict__ ss = start + (size_t)sd * CELLS;
    const float4* __restrict__ db = sorted + (size_t)sd * N_PTS;

    float best = 3.402823466e38f;
    int done = 0;
    for (int r = 0; r < G; ++r) {
        if (!done) {
            for (int dz = -r; dz <= r; ++dz) {
                int Z = cz + dz;
                if ((unsigned)Z >= G) continue;
                int adz = (dz < 0) ? -dz : dz;
                for (int dy = -r; dy <= r; ++dy) {
                    int Y = cy + dy;
                    if ((unsigned)Y >= G) continue;
                    int ady = (dy < 0) ? -dy : dy;
                    int inner_yz = (adz < r) && (ady < r);
                    for (int dx = -r; dx <= r; ++dx) {
                        int adx = (dx < 0) ? -dx : dx;
                        if (inner_yz && adx < r) continue;   // Chebyshev < r: done
                        int X = cx + dx;
                        if ((unsigned)X >= G) continue;
                        int c = (Z * G + Y) * G + X;
                        unsigned int n  = cs[c];
                        unsigned int st = ss[c];
                        for (unsigned int k = 0; k < n; ++k) {
                            float4 t = db[st + k];
                            float ddx = qx - t.x, ddy = qy - t.y, ddz = qz - t.z;
                            float d2 = ddx * ddx + ddy * ddy + ddz * ddz;
                            best = fminf(best, d2);
                        }
                    }
                }
            }
        }
        float bound = (float)r * CELLH;
        done = done | (best <= bound * bound);
        if (__all(done)) break;
    }
    nnd2[q] = best;
}

__global__ __launch_bounds__(256) void chamfer_reduce(const float* __restrict__ nnd2,
                                                      float* __restrict__ accum,
                                                      unsigned int* __restrict__ counter,
                                                      float* __restrict__ out) {
    const int i = blockIdx.x * 256 + threadIdx.x;   // < TOTQ
    float v = sqrtf(nnd2[i]);

    for (int off = 32; off > 0; off >>= 1)
        v += __shfl_down(v, off, 64);

    __shared__ float wsum[4];
    const int wave = threadIdx.x >> 6;
    if ((threadIdx.x & 63) == 0) wsum[wave] = v;
    __syncthreads();
    if (threadIdx.x == 0) {
        atomicAdd(accum, wsum[0] + wsum[1] + wsum[2] + wsum[3]);
        __threadfence();
        unsigned int old = atomicAdd(counter, 1u);
        if (old == RBLK - 1) {
            float total = atomicAdd(accum, 0.0f);   // coherent read after all adds
            out[0] = total * (1.0f / (float)(BATCH * N_PTS));
        }
    }
}

extern "C" void kernel_launch(void* const* d_in, const int* in_sizes, int n_in,
                              void* d_out, int out_size, void* d_ws, size_t ws_size,
                              hipStream_t stream) {
    const float* pc1  = (const float*)d_in[0];
    const float* pc2  = (const float*)d_in[1];
    const float* flow = (const float*)d_in[2];
    float* out = (float*)d_out;

    float4* pts    = (float4*)d_ws;
    float4* sorted = pts + (size_t)NSETS * N_PTS;
    unsigned int* cnt    = (unsigned int*)(sorted + (size_t)NSETS * N_PTS);
    unsigned int* start  = cnt + NSETS * CELLS;
    unsigned int* cursor = start + NSETS * CELLS;
    float* nnd2 = (float*)(cursor + NSETS * CELLS);
    float* accum = nnd2 + TOTQ;
    unsigned int* counter = (unsigned int*)(accum + 1);

    grid_zero<<<(NSETS * CELLS + 255) / 256, 256, 0, stream>>>(cnt, accum, counter);
    grid_prep<<<(BATCH * N_PTS + 255) / 256, 256, 0, stream>>>(pc1, pc2, flow, pts, cnt);
    grid_scan<<<NSETS, 1024, 0, stream>>>(cnt, start, cursor);
    grid_scatter<<<(NSETS * N_PTS + 255) / 256, 256, 0, stream>>>(pts, cursor, sorted);
    grid_query<<<TOTQ / 64, 64, 0, stream>>>(pts, cnt, start, sorted, nnd2);
    chamfer_reduce<<<RBLK, 256, 0, stream>>>(nnd2, accum, counter, out);
}

// Round 9
// 273.513 us; speedup vs baseline: 2.5159x; 2.5159x over previous
//
#include <hip/hip_runtime.h>
#include <math.h>

#define N_PTS  8192
#define BATCH  2
#define NSETS  4                 // s = b*2 + t ; t=0: pc2, t=1: warped pc1
#define G      32
#define CELLS  (G * G * G)       // 32768
#define BOXLO  (-6.5f)
#define CELLH  0.40625f          // 13/32
#define INVH   (1.0f / CELLH)
#define TOTQ   (2 * BATCH * N_PTS)   // 32768 queries
#define RBLK   (TOTQ / 256)          // 128 reduce blocks

// ws layout (all rewritten every call; poison-safe):
//   pts    float4[NSETS*N_PTS]  raw points, .w = cell-id bits        (512 KB)
//   sorted float4[NSETS*N_PTS]  cell-sorted points                   (512 KB)
//   cnt    uint[NSETS*CELLS]                                         (512 KB)
//   start  uint[NSETS*CELLS]    exclusive scan of cnt                (512 KB)
//   cursor uint[NSETS*CELLS]    scatter cursors (init = start)       (512 KB)
//   nnd2   float[TOTQ]          per-query min d^2                    (128 KB)
//   accum  float, counter uint

__device__ __forceinline__ int cell_of(float x, float y, float z) {
    int cx = (int)floorf((x - BOXLO) * INVH);
    int cy = (int)floorf((y - BOXLO) * INVH);
    int cz = (int)floorf((z - BOXLO) * INVH);
    cx = min(max(cx, 0), G - 1);
    cy = min(max(cy, 0), G - 1);
    cz = min(max(cz, 0), G - 1);
    return (cz * G + cy) * G + cx;
}

__global__ __launch_bounds__(256) void grid_zero(unsigned int* __restrict__ cnt,
                                                 float* __restrict__ accum,
                                                 unsigned int* __restrict__ counter) {
    int i = blockIdx.x * 256 + threadIdx.x;
    if (i < NSETS * CELLS) cnt[i] = 0u;
    if (i == 0) { *accum = 0.0f; *counter = 0u; }
}

__global__ __launch_bounds__(256) void grid_prep(const float* __restrict__ pc1,
                                                 const float* __restrict__ pc2,
                                                 const float* __restrict__ flow,
                                                 float4* __restrict__ pts,
                                                 unsigned int* __restrict__ cnt) {
    int i = blockIdx.x * 256 + threadIdx.x;      // 0 .. BATCH*N_PTS-1
    if (i >= BATCH * N_PTS) return;
    int b = i >> 13, j = i & (N_PTS - 1);

    float px = pc2[i * 3 + 0], py = pc2[i * 3 + 1], pz = pc2[i * 3 + 2];
    int c0 = cell_of(px, py, pz);
    pts[(size_t)(b * 2 + 0) * N_PTS + j] =
        make_float4(px, py, pz, __uint_as_float((unsigned)c0));
    atomicAdd(&cnt[(b * 2 + 0) * CELLS + c0], 1u);

    float wx = pc1[i * 3 + 0] + flow[i * 3 + 0];
    float wy = pc1[i * 3 + 1] + flow[i * 3 + 1];
    float wz = pc1[i * 3 + 2] + flow[i * 3 + 2];
    int c1 = cell_of(wx, wy, wz);
    pts[(size_t)(b * 2 + 1) * N_PTS + j] =
        make_float4(wx, wy, wz, __uint_as_float((unsigned)c1));
    atomicAdd(&cnt[(b * 2 + 1) * CELLS + c1], 1u);
}

// One block per set: exclusive scan of 32768 counts (32 per thread, 1024 thr).
__global__ __launch_bounds__(1024) void grid_scan(const unsigned int* __restrict__ cnt,
                                                  unsigned int* __restrict__ start,
                                                  unsigned int* __restrict__ cursor) {
    __shared__ unsigned int tsum[1024];
    const int s   = blockIdx.x;
    const int tid = threadIdx.x;
    const unsigned int* c = cnt + (size_t)s * CELLS;

    unsigned int v[32];
    unsigned int sum = 0;
    #pragma unroll
    for (int k = 0; k < 32; ++k) { v[k] = c[tid * 32 + k]; sum += v[k]; }
    tsum[tid] = sum;
    __syncthreads();
    // Hillis-Steele inclusive scan over 1024 partials
    for (int off = 1; off < 1024; off <<= 1) {
        unsigned int add = (tid >= off) ? tsum[tid - off] : 0u;
        __syncthreads();
        tsum[tid] += add;
        __syncthreads();
    }
    unsigned int base = (tid == 0) ? 0u : tsum[tid - 1];
    size_t o = (size_t)s * CELLS + tid * 32;
    #pragma unroll
    for (int k = 0; k < 32; ++k) {
        start[o + k]  = base;
        cursor[o + k] = base;
        base += v[k];
    }
}

__global__ __launch_bounds__(256) void grid_scatter(const float4* __restrict__ pts,
                                                    unsigned int* __restrict__ cursor,
                                                    float4* __restrict__ sorted) {
    int i = blockIdx.x * 256 + threadIdx.x;      // 0 .. NSETS*N_PTS-1
    if (i >= NSETS * N_PTS) return;
    int s = i >> 13;
    float4 p = pts[i];
    unsigned int cell = __float_as_uint(p.w);
    unsigned int pos  = atomicAdd(&cursor[s * CELLS + cell], 1u);
    sorted[(size_t)s * N_PTS + pos] = p;
}

// Exact 1-NN via expanding Chebyshev shells over a 32^3 grid. Queries are
// processed in CELL-SORTED order: a wave's 64 lanes sit in the same/adjacent
// cells, so candidate loads are wave-broadcast L1 hits and shell divergence
// collapses. Stop rule: after completing shell r, every unsearched cell is
// Chebyshev >= r+1 away; the clamp is 1-Lipschitz, so any point there is
// >= r*CELLH away. Exact.
__global__ __launch_bounds__(64) void grid_query(const unsigned int* __restrict__ cnt,
                                                 const unsigned int* __restrict__ start,
                                                 const float4* __restrict__ sorted,
                                                 float* __restrict__ nnd2) {
    const int q  = blockIdx.x * 64 + threadIdx.x;   // < TOTQ (= NSETS*N_PTS)
    const int s  = q >> 13;                         // query set
    const int sd = s ^ 1;                           // DB set (same batch, other cloud)

    const float4 p = sorted[q];                     // cell-sorted query stream
    const float qx = p.x, qy = p.y, qz = p.z;
    const unsigned int qcell = __float_as_uint(p.w);
    const int cx = qcell & (G - 1);
    const int cy = (qcell >> 5) & (G - 1);
    const int cz = qcell >> 10;

    const unsigned int* __restrict__ cs = cnt   + (size_t)sd * CELLS;
    const unsigned int* __restrict__ ss = start + (size_t)sd * CELLS;
    const float4* __restrict__ db = sorted + (size_t)sd * N_PTS;

    float best = 3.402823466e38f;
    int done = 0;
    for (int r = 0; r < G; ++r) {
        if (!done) {
            for (int dz = -r; dz <= r; ++dz) {
                int Z = cz + dz;
                if ((unsigned)Z >= G) continue;
                int adz = (dz < 0) ? -dz : dz;
                for (int dy = -r; dy <= r; ++dy) {
                    int Y = cy + dy;
                    if ((unsigned)Y >= G) continue;
                    int ady = (dy < 0) ? -dy : dy;
                    int inner_yz = (adz < r) && (ady < r);
                    for (int dx = -r; dx <= r; ++dx) {
                        int adx = (dx < 0) ? -dx : dx;
                        if (inner_yz && adx < r) continue;   // interior: already done
                        int X = cx + dx;
                        if ((unsigned)X >= G) continue;
                        int c = (Z * G + Y) * G + X;
                        unsigned int n  = cs[c];
                        unsigned int st = ss[c];
                        for (unsigned int k = 0; k < n; ++k) {
                            float4 t = db[st + k];
                            float ddx = qx - t.x, ddy = qy - t.y, ddz = qz - t.z;
                            float d2 = ddx * ddx + ddy * ddy + ddz * ddz;
                            best = fminf(best, d2);
                        }
                    }
                }
            }
        }
        float bound = (float)r * CELLH;
        done = done | (best <= bound * bound);
        if (__all(done)) break;
    }
    nnd2[q] = best;
}

__global__ __launch_bounds__(256) void chamfer_reduce(const float* __restrict__ nnd2,
                                                      float* __restrict__ accum,
                                                      unsigned int* __restrict__ counter,
                                                      float* __restrict__ out) {
    const int i = blockIdx.x * 256 + threadIdx.x;   // < TOTQ
    float v = sqrtf(nnd2[i]);

    for (int off = 32; off > 0; off >>= 1)
        v += __shfl_down(v, off, 64);

    __shared__ float wsum[4];
    const int wave = threadIdx.x >> 6;
    if ((threadIdx.x & 63) == 0) wsum[wave] = v;
    __syncthreads();
    if (threadIdx.x == 0) {
        atomicAdd(accum, wsum[0] + wsum[1] + wsum[2] + wsum[3]);
        __threadfence();
        unsigned int old = atomicAdd(counter, 1u);
        if (old == RBLK - 1) {
            float total = atomicAdd(accum, 0.0f);   // coherent read after all adds
            out[0] = total * (1.0f / (float)(BATCH * N_PTS));
        }
    }
}

extern "C" void kernel_launch(void* const* d_in, const int* in_sizes, int n_in,
                              void* d_out, int out_size, void* d_ws, size_t ws_size,
                              hipStream_t stream) {
    const float* pc1  = (const float*)d_in[0];
    const float* pc2  = (const float*)d_in[1];
    const float* flow = (const float*)d_in[2];
    float* out = (float*)d_out;

    float4* pts    = (float4*)d_ws;
    float4* sorted = pts + (size_t)NSETS * N_PTS;
    unsigned int* cnt    = (unsigned int*)(sorted + (size_t)NSETS * N_PTS);
    unsigned int* start  = cnt + NSETS * CELLS;
    unsigned int* cursor = start + NSETS * CELLS;
    float* nnd2 = (float*)(cursor + NSETS * CELLS);
    float* accum = nnd2 + TOTQ;
    unsigned int* counter = (unsigned int*)(accum + 1);

    grid_zero<<<(NSETS * CELLS + 255) / 256, 256, 0, stream>>>(cnt, accum, counter);
    grid_prep<<<(BATCH * N_PTS + 255) / 256, 256, 0, stream>>>(pc1, pc2, flow, pts, cnt);
    grid_scan<<<NSETS, 1024, 0, stream>>>(cnt, start, cursor);
    grid_scatter<<<(NSETS * N_PTS + 255) / 256, 256, 0, stream>>>(pts, cursor, sorted);
    grid_query<<<TOTQ / 64, 64, 0, stream>>>(cnt, start, sorted, nnd2);
    chamfer_reduce<<<RBLK, 256, 0, stream>>>(nnd2, accum, counter, out);
}

// Round 10
// 87.577 us; speedup vs baseline: 7.8573x; 3.1231x over previous
//
#include <hip/hip_runtime.h>
#include <math.h>

#define N_PTS  8192
#define BATCH  2
#define NSETS  4                 // s = b*2 + t ; t=0: pc2, t=1: warped pc1
#define G      32
#define CELLS  (G * G * G)       // 32768
#define BOXLO  (-6.5f)
#define CELLH  0.40625f          // 13/32, exact in binary
#define INVH   (1.0f / CELLH)
#define H2     (CELLH * CELLH)
#define TOTQ   (NSETS * N_PTS)   // 32768 queries (both dirs, both batches)
#define RBLK   (TOTQ / 256)      // 128 reduce blocks
#define FARBLK 512
#define FARWAVES (FARBLK * 4)    // 2048 waves for straggler pass

// ws layout (all rewritten every call; poison-safe):
//   pts    float4[NSETS*N_PTS]   raw points, .w = cell-id bits       (512 KB)
//   sorted float4[NSETS*N_PTS]   cell-sorted points                  (512 KB)
//   cnt    uint [NSETS*CELLS]                                        (512 KB)
//   meta   uint2[NSETS*CELLS]    (start, count) per cell               (1 MB)
//   cursor uint [NSETS*CELLS]    scatter cursors                     (512 KB)
//   nnd2   float[TOTQ]           per-query min d^2                   (128 KB)
//   strag  uint [TOTQ]           straggler query ids                 (128 KB)
//   stragn uint, accum float, counter uint

__device__ __forceinline__ int cell_of(float x, float y, float z) {
    int cx = (int)floorf((x - BOXLO) * INVH);
    int cy = (int)floorf((y - BOXLO) * INVH);
    int cz = (int)floorf((z - BOXLO) * INVH);
    cx = min(max(cx, 0), G - 1);
    cy = min(max(cy, 0), G - 1);
    cz = min(max(cz, 0), G - 1);
    return (cz * G + cy) * G + cx;
}

__global__ __launch_bounds__(256) void grid_zero(unsigned int* __restrict__ cnt,
                                                 unsigned int* __restrict__ stragn,
                                                 float* __restrict__ accum,
                                                 unsigned int* __restrict__ counter) {
    int i = blockIdx.x * 256 + threadIdx.x;
    if (i < NSETS * CELLS) cnt[i] = 0u;
    if (i == 0) { *stragn = 0u; *accum = 0.0f; *counter = 0u; }
}

__global__ __launch_bounds__(256) void grid_prep(const float* __restrict__ pc1,
                                                 const float* __restrict__ pc2,
                                                 const float* __restrict__ flow,
                                                 float4* __restrict__ pts,
                                                 unsigned int* __restrict__ cnt) {
    int i = blockIdx.x * 256 + threadIdx.x;      // 0 .. BATCH*N_PTS-1
    if (i >= BATCH * N_PTS) return;
    int b = i >> 13, j = i & (N_PTS - 1);

    float px = pc2[i * 3 + 0], py = pc2[i * 3 + 1], pz = pc2[i * 3 + 2];
    int c0 = cell_of(px, py, pz);
    pts[(size_t)(b * 2 + 0) * N_PTS + j] =
        make_float4(px, py, pz, __uint_as_float((unsigned)c0));
    atomicAdd(&cnt[(b * 2 + 0) * CELLS + c0], 1u);

    float wx = pc1[i * 3 + 0] + flow[i * 3 + 0];
    float wy = pc1[i * 3 + 1] + flow[i * 3 + 1];
    float wz = pc1[i * 3 + 2] + flow[i * 3 + 2];
    int c1 = cell_of(wx, wy, wz);
    pts[(size_t)(b * 2 + 1) * N_PTS + j] =
        make_float4(wx, wy, wz, __uint_as_float((unsigned)c1));
    atomicAdd(&cnt[(b * 2 + 1) * CELLS + c1], 1u);
}

// One block per set: exclusive scan of 32768 counts (32/thread, 1024 thr).
__global__ __launch_bounds__(1024) void grid_scan(const unsigned int* __restrict__ cnt,
                                                  uint2* __restrict__ meta,
                                                  unsigned int* __restrict__ cursor) {
    __shared__ unsigned int tsum[1024];
    const int s   = blockIdx.x;
    const int tid = threadIdx.x;
    const unsigned int* c = cnt + (size_t)s * CELLS;

    unsigned int v[32];
    unsigned int sum = 0;
    #pragma unroll
    for (int k = 0; k < 32; ++k) { v[k] = c[tid * 32 + k]; sum += v[k]; }
    tsum[tid] = sum;
    __syncthreads();
    for (int off = 1; off < 1024; off <<= 1) {
        unsigned int add = (tid >= off) ? tsum[tid - off] : 0u;
        __syncthreads();
        tsum[tid] += add;
        __syncthreads();
    }
    unsigned int base = (tid == 0) ? 0u : tsum[tid - 1];
    size_t o = (size_t)s * CELLS + tid * 32;
    #pragma unroll
    for (int k = 0; k < 32; ++k) {
        meta[o + k]   = make_uint2(base, v[k]);
        cursor[o + k] = base;
        base += v[k];
    }
}

__global__ __launch_bounds__(256) void grid_scatter(const float4* __restrict__ pts,
                                                    unsigned int* __restrict__ cursor,
                                                    float4* __restrict__ sorted) {
    int i = blockIdx.x * 256 + threadIdx.x;      // 0 .. NSETS*N_PTS-1
    if (i >= NSETS * N_PTS) return;
    int s = i >> 13;
    float4 p = pts[i];
    unsigned int cell = __float_as_uint(p.w);
    unsigned int pos  = atomicAdd(&cursor[s * CELLS + cell], 1u);
    sorted[(size_t)s * N_PTS + pos] = p;
}

// Pass 1: each query gets 4 lanes; the 27-cell 3x3x3 neighborhood is split
// across the lanes (static 7-iteration unrolled loop -> independent meta
// loads, ILP). If best2 <= H2 the NN is exact: any point in a cell with
// Chebyshev distance >= 2 is at least CELLH away (clamp is monotone and
// 1-Lipschitz per axis). Otherwise the query is appended to the straggler
// list for the brute-force pass.
__global__ __launch_bounds__(256) void query_near(const uint2* __restrict__ meta,
                                                  const float4* __restrict__ sorted,
                                                  float* __restrict__ nnd2,
                                                  unsigned int* __restrict__ strag,
                                                  unsigned int* __restrict__ stragn) {
    const int gid = blockIdx.x * 256 + threadIdx.x;   // < 4*TOTQ
    const int q   = gid >> 2;
    const int sub = gid & 3;
    const int sd  = (q >> 13) ^ 1;                    // DB set

    const float4 p = sorted[q];                       // cell-sorted query stream
    const float qx = p.x, qy = p.y, qz = p.z;
    const unsigned int qcell = __float_as_uint(p.w);
    const int cx = qcell & (G - 1);
    const int cy = (qcell >> 5) & (G - 1);
    const int cz = qcell >> 10;

    const uint2*  __restrict__ mt = meta   + (size_t)sd * CELLS;
    const float4* __restrict__ db = sorted + (size_t)sd * N_PTS;

    float best = 3.402823466e38f;
    #pragma unroll
    for (int k = 0; k < 7; ++k) {
        const int cc = sub + k * 4;                   // lane sub takes cells sub, sub+4, ...
        if (cc < 27) {
            int dzz = cc / 9, rem = cc - dzz * 9;
            int dyy = rem / 3, dxx = rem - dyy * 3;
            int Z = cz + dzz - 1, Y = cy + dyy - 1, X = cx + dxx - 1;
            if ((unsigned)X < G && (unsigned)Y < G && (unsigned)Z < G) {
                uint2 m = mt[(Z * G + Y) * G + X];
                for (unsigned int j = 0; j < m.y; ++j) {
                    float4 t = db[m.x + j];
                    float ddx = qx - t.x, ddy = qy - t.y, ddz = qz - t.z;
                    best = fminf(best, ddx * ddx + ddy * ddy + ddz * ddz);
                }
            }
        }
    }
    // reduce across the 4 lanes of this query (groups are wave-aligned)
    best = fminf(best, __shfl_xor(best, 1, 64));
    best = fminf(best, __shfl_xor(best, 2, 64));
    if (sub == 0) {
        nnd2[q] = best;
        if (best > H2) {
            unsigned int idx = atomicAdd(stragn, 1u);
            strag[idx] = (unsigned int)q;
        }
    }
}

// Pass 2: one wave per straggler, full-DB brute force, 64-lane coalesced
// split + butterfly min. Deterministic: each wave writes only its query.
__global__ __launch_bounds__(256) void query_far(const unsigned int* __restrict__ strag,
                                                 const unsigned int* __restrict__ stragn,
                                                 const float4* __restrict__ sorted,
                                                 float* __restrict__ nnd2) {
    const int wid  = (blockIdx.x * 256 + threadIdx.x) >> 6;
    const int lane = threadIdx.x & 63;
    const unsigned int n = *stragn;
    for (unsigned int t = wid; t < n; t += FARWAVES) {
        const int q  = (int)strag[t];
        const int sd = (q >> 13) ^ 1;
        const float4 p = sorted[q];
        const float4* __restrict__ db = sorted + (size_t)sd * N_PTS;
        float b0 = 3.402823466e38f, b1 = b0, b2 = b0, b3 = b0;
        for (int j = lane; j < N_PTS; j += 256) {
            float4 t0 = db[j];
            float4 t1 = db[j + 64];
            float4 t2 = db[j + 128];
            float4 t3 = db[j + 192];
            float dx0 = p.x - t0.x, dy0 = p.y - t0.y, dz0 = p.z - t0.z;
            float dx1 = p.x - t1.x, dy1 = p.y - t1.y, dz1 = p.z - t1.z;
            float dx2 = p.x - t2.x, dy2 = p.y - t2.y, dz2 = p.z - t2.z;
            float dx3 = p.x - t3.x, dy3 = p.y - t3.y, dz3 = p.z - t3.z;
            b0 = fminf(b0, dx0 * dx0 + dy0 * dy0 + dz0 * dz0);
            b1 = fminf(b1, dx1 * dx1 + dy1 * dy1 + dz1 * dz1);
            b2 = fminf(b2, dx2 * dx2 + dy2 * dy2 + dz2 * dz2);
            b3 = fminf(b3, dx3 * dx3 + dy3 * dy3 + dz3 * dz3);
        }
        float best = fminf(fminf(b0, b1), fminf(b2, b3));
        #pragma unroll
        for (int off = 1; off < 64; off <<= 1)
            best = fminf(best, __shfl_xor(best, off, 64));
        if (lane == 0) nnd2[q] = best;
    }
}

__global__ __launch_bounds__(256) void chamfer_reduce(const float* __restrict__ nnd2,
                                                      float* __restrict__ accum,
                                                      unsigned int* __restrict__ counter,
                                                      float* __restrict__ out) {
    const int i = blockIdx.x * 256 + threadIdx.x;   // < TOTQ
    float v = sqrtf(nnd2[i]);

    for (int off = 32; off > 0; off >>= 1)
        v += __shfl_down(v, off, 64);

    __shared__ float wsum[4];
    const int wave = threadIdx.x >> 6;
    if ((threadIdx.x & 63) == 0) wsum[wave] = v;
    __syncthreads();
    if (threadIdx.x == 0) {
        atomicAdd(accum, wsum[0] + wsum[1] + wsum[2] + wsum[3]);
        __threadfence();
        unsigned int old = atomicAdd(counter, 1u);
        if (old == RBLK - 1) {
            float total = atomicAdd(accum, 0.0f);   // coherent read after all adds
            out[0] = total * (1.0f / (float)(BATCH * N_PTS));
        }
    }
}

extern "C" void kernel_launch(void* const* d_in, const int* in_sizes, int n_in,
                              void* d_out, int out_size, void* d_ws, size_t ws_size,
                              hipStream_t stream) {
    const float* pc1  = (const float*)d_in[0];
    const float* pc2  = (const float*)d_in[1];
    const float* flow = (const float*)d_in[2];
    float* out = (float*)d_out;

    float4* pts    = (float4*)d_ws;
    float4* sorted = pts + (size_t)NSETS * N_PTS;
    unsigned int* cnt    = (unsigned int*)(sorted + (size_t)NSETS * N_PTS);
    uint2* meta          = (uint2*)(cnt + (size_t)NSETS * CELLS);
    unsigned int* cursor = (unsigned int*)(meta + (size_t)NSETS * CELLS);
    float* nnd2          = (float*)(cursor + (size_t)NSETS * CELLS);
    unsigned int* strag  = (unsigned int*)(nnd2 + TOTQ);
    unsigned int* stragn = strag + TOTQ;
    float* accum         = (float*)(stragn + 1);
    unsigned int* counter = (unsigned int*)(accum + 1);

    grid_zero<<<(NSETS * CELLS + 255) / 256, 256, 0, stream>>>(cnt, stragn, accum, counter);
    grid_prep<<<(BATCH * N_PTS + 255) / 256, 256, 0, stream>>>(pc1, pc2, flow, pts, cnt);
    grid_scan<<<NSETS, 1024, 0, stream>>>(cnt, meta, cursor);
    grid_scatter<<<(NSETS * N_PTS + 255) / 256, 256, 0, stream>>>(pts, cursor, sorted);
    query_near<<<(4 * TOTQ) / 256, 256, 0, stream>>>(meta, sorted, nnd2, strag, stragn);
    query_far<<<FARBLK, 256, 0, stream>>>(strag, stragn, sorted, nnd2);
    chamfer_reduce<<<RBLK, 256, 0, stream>>>(nnd2, accum, counter, out);
}

// Round 11
// 81.508 us; speedup vs baseline: 8.4424x; 1.0745x over previous
//
#include <hip/hip_runtime.h>
#include <math.h>

#define N_PTS  8192
#define BATCH  2
#define NSETS  4                 // s = b*2 + t ; t=0: pc2, t=1: warped pc1
#define G      32
#define CELLS  (G * G * G)       // 32768
#define BOXLO  (-6.5f)
#define CELLH  0.40625f          // 13/32, exact in binary
#define INVH   (1.0f / CELLH)
#define H2     (CELLH * CELLH)
#define TOTQ   (NSETS * N_PTS)   // 32768 queries (both dirs, both batches)
#define RBLK   (TOTQ / 256)      // 128 reduce blocks
#define FARBLK 512
#define FARWAVES (FARBLK * 4)    // 2048 waves for straggler pass

// ws layout (all rewritten every call; poison-safe):
//   pts    float4[NSETS*N_PTS]   raw points, .w = cell-id bits       (512 KB)
//   sorted float4[NSETS*N_PTS]   cell-sorted points                  (512 KB)
//   cnt    uint [NSETS*CELLS]                                        (512 KB)
//   meta   uint2[NSETS*CELLS]    (start, count) per cell               (1 MB)
//   cursor uint [NSETS*CELLS]    scatter cursors                     (512 KB)
//   nnd2   float[TOTQ]           per-query min d^2                   (128 KB)
//   strag  uint [TOTQ]           straggler query ids                 (128 KB)
//   stragn uint, accum float, counter uint

__device__ __forceinline__ int cell_of(float x, float y, float z) {
    int cx = (int)floorf((x - BOXLO) * INVH);
    int cy = (int)floorf((y - BOXLO) * INVH);
    int cz = (int)floorf((z - BOXLO) * INVH);
    cx = min(max(cx, 0), G - 1);
    cy = min(max(cy, 0), G - 1);
    cz = min(max(cz, 0), G - 1);
    return (cz * G + cy) * G + cx;
}

__global__ __launch_bounds__(256) void grid_zero(unsigned int* __restrict__ cnt,
                                                 unsigned int* __restrict__ stragn,
                                                 float* __restrict__ accum,
                                                 unsigned int* __restrict__ counter) {
    int i = blockIdx.x * 256 + threadIdx.x;
    if (i < NSETS * CELLS) cnt[i] = 0u;
    if (i == 0) { *stragn = 0u; *accum = 0.0f; *counter = 0u; }
}

__global__ __launch_bounds__(256) void grid_prep(const float* __restrict__ pc1,
                                                 const float* __restrict__ pc2,
                                                 const float* __restrict__ flow,
                                                 float4* __restrict__ pts,
                                                 unsigned int* __restrict__ cnt) {
    int i = blockIdx.x * 256 + threadIdx.x;      // 0 .. BATCH*N_PTS-1
    if (i >= BATCH * N_PTS) return;
    int b = i >> 13, j = i & (N_PTS - 1);

    float px = pc2[i * 3 + 0], py = pc2[i * 3 + 1], pz = pc2[i * 3 + 2];
    int c0 = cell_of(px, py, pz);
    pts[(size_t)(b * 2 + 0) * N_PTS + j] =
        make_float4(px, py, pz, __uint_as_float((unsigned)c0));
    atomicAdd(&cnt[(b * 2 + 0) * CELLS + c0], 1u);

    float wx = pc1[i * 3 + 0] + flow[i * 3 + 0];
    float wy = pc1[i * 3 + 1] + flow[i * 3 + 1];
    float wz = pc1[i * 3 + 2] + flow[i * 3 + 2];
    int c1 = cell_of(wx, wy, wz);
    pts[(size_t)(b * 2 + 1) * N_PTS + j] =
        make_float4(wx, wy, wz, __uint_as_float((unsigned)c1));
    atomicAdd(&cnt[(b * 2 + 1) * CELLS + c1], 1u);
}

// One block per set: exclusive scan of 32768 counts (32/thread, 1024 thr).
// Wave-shuffle scan: 2 barriers total instead of 20.
__global__ __launch_bounds__(1024) void grid_scan(const unsigned int* __restrict__ cnt,
                                                  uint2* __restrict__ meta,
                                                  unsigned int* __restrict__ cursor) {
    __shared__ unsigned int wtot[16];
    const int s    = blockIdx.x;
    const int tid  = threadIdx.x;
    const int lane = tid & 63;
    const int wv   = tid >> 6;
    const unsigned int* c = cnt + (size_t)s * CELLS;

    unsigned int v[32];
    unsigned int sum = 0;
    #pragma unroll
    for (int k = 0; k < 32; ++k) { v[k] = c[tid * 32 + k]; sum += v[k]; }

    // inclusive scan of per-thread sums within the wave
    unsigned int isc = sum;
    #pragma unroll
    for (int off = 1; off < 64; off <<= 1) {
        unsigned int t = __shfl_up(isc, off, 64);
        if (lane >= off) isc += t;
    }
    if (lane == 63) wtot[wv] = isc;
    __syncthreads();
    if (tid < 16) {     // inclusive scan of 16 wave totals (width-16 subgroup)
        unsigned int w = wtot[tid];
        #pragma unroll
        for (int off = 1; off < 16; off <<= 1) {
            unsigned int t = __shfl_up(w, off, 16);
            if (tid >= off) w += t;
        }
        wtot[tid] = w;
    }
    __syncthreads();

    unsigned int base = (wv ? wtot[wv - 1] : 0u) + (isc - sum);  // exclusive
    size_t o = (size_t)s * CELLS + tid * 32;
    #pragma unroll
    for (int k = 0; k < 32; ++k) {
        meta[o + k]   = make_uint2(base, v[k]);
        cursor[o + k] = base;
        base += v[k];
    }
}

__global__ __launch_bounds__(256) void grid_scatter(const float4* __restrict__ pts,
                                                    unsigned int* __restrict__ cursor,
                                                    float4* __restrict__ sorted) {
    int i = blockIdx.x * 256 + threadIdx.x;      // 0 .. NSETS*N_PTS-1
    if (i >= NSETS * N_PTS) return;
    int s = i >> 13;
    float4 p = pts[i];
    unsigned int cell = __float_as_uint(p.w);
    unsigned int pos  = atomicAdd(&cursor[s * CELLS + cell], 1u);
    sorted[(size_t)s * N_PTS + pos] = p;
}

// Pass 1: 8 lanes per query; the 27-cell 3x3x3 neighborhood splits across
// lanes (<=4 cells each). Phase A prefetches all cell metas into registers
// (independent loads, ILP); phase B runs the candidate loops. If best2 <= H2
// the NN is exact (cells Chebyshev >=2 away are >= CELLH distant; the cell
// clamp is monotone so index-diff>=2 still implies coord-diff > CELLH).
// Stragglers go to the brute-force pass.
__global__ __launch_bounds__(256) void query_near(const uint2* __restrict__ meta,
                                                  const float4* __restrict__ sorted,
                                                  float* __restrict__ nnd2,
                                                  unsigned int* __restrict__ strag,
                                                  unsigned int* __restrict__ stragn) {
    const int gid = blockIdx.x * 256 + threadIdx.x;   // < 8*TOTQ
    const int q   = gid >> 3;
    const int sub = gid & 7;
    const int sd  = (q >> 13) ^ 1;                    // DB set

    const float4 p = sorted[q];                       // cell-sorted query stream
    const float qx = p.x, qy = p.y, qz = p.z;
    const unsigned int qcell = __float_as_uint(p.w);
    const int cx = qcell & (G - 1);
    const int cy = (qcell >> 5) & (G - 1);
    const int cz = qcell >> 10;

    const uint2*  __restrict__ mt = meta   + (size_t)sd * CELLS;
    const float4* __restrict__ db = sorted + (size_t)sd * N_PTS;

    // Phase A: prefetch up to 4 cell metas into named registers.
    unsigned int st0 = 0, n0 = 0, st1 = 0, n1 = 0, st2 = 0, n2 = 0, st3 = 0, n3 = 0;
    #pragma unroll
    for (int k = 0; k < 4; ++k) {
        const int cc = sub + k * 8;                   // 0..31; only cc<27 valid
        if (cc < 27) {
            int dzz = cc / 9, rem = cc - dzz * 9;
            int dyy = rem / 3, dxx = rem - dyy * 3;
            int Z = cz + dzz - 1, Y = cy + dyy - 1, X = cx + dxx - 1;
            if ((unsigned)X < G && (unsigned)Y < G && (unsigned)Z < G) {
                uint2 m = mt[(Z * G + Y) * G + X];
                if (k == 0) { st0 = m.x; n0 = m.y; }
                if (k == 1) { st1 = m.x; n1 = m.y; }
                if (k == 2) { st2 = m.x; n2 = m.y; }
                if (k == 3) { st3 = m.x; n3 = m.y; }
            }
        }
    }

    // Phase B: candidate loops.
    float best = 3.402823466e38f;
    for (unsigned int j = 0; j < n0; ++j) {
        float4 t = db[st0 + j];
        float ddx = qx - t.x, ddy = qy - t.y, ddz = qz - t.z;
        best = fminf(best, ddx * ddx + ddy * ddy + ddz * ddz);
    }
    for (unsigned int j = 0; j < n1; ++j) {
        float4 t = db[st1 + j];
        float ddx = qx - t.x, ddy = qy - t.y, ddz = qz - t.z;
        best = fminf(best, ddx * ddx + ddy * ddy + ddz * ddz);
    }
    for (unsigned int j = 0; j < n2; ++j) {
        float4 t = db[st2 + j];
        float ddx = qx - t.x, ddy = qy - t.y, ddz = qz - t.z;
        best = fminf(best, ddx * ddx + ddy * ddy + ddz * ddz);
    }
    for (unsigned int j = 0; j < n3; ++j) {
        float4 t = db[st3 + j];
        float ddx = qx - t.x, ddy = qy - t.y, ddz = qz - t.z;
        best = fminf(best, ddx * ddx + ddy * ddy + ddz * ddz);
    }

    // reduce across the 8 lanes of this query (groups are wave-aligned)
    best = fminf(best, __shfl_xor(best, 1, 64));
    best = fminf(best, __shfl_xor(best, 2, 64));
    best = fminf(best, __shfl_xor(best, 4, 64));
    if (sub == 0) {
        nnd2[q] = best;
        if (best > H2) {
            unsigned int idx = atomicAdd(stragn, 1u);
            strag[idx] = (unsigned int)q;
        }
    }
}

// Pass 2: one wave per straggler, full-DB brute force, 64-lane coalesced
// split + butterfly min. Deterministic: each wave writes only its query.
__global__ __launch_bounds__(256) void query_far(const unsigned int* __restrict__ strag,
                                                 const unsigned int* __restrict__ stragn,
                                                 const float4* __restrict__ sorted,
                                                 float* __restrict__ nnd2) {
    const int wid  = (blockIdx.x * 256 + threadIdx.x) >> 6;
    const int lane = threadIdx.x & 63;
    const unsigned int n = *stragn;
    for (unsigned int t = wid; t < n; t += FARWAVES) {
        const int q  = (int)strag[t];
        const int sd = (q >> 13) ^ 1;
        const float4 p = sorted[q];
        const float4* __restrict__ db = sorted + (size_t)sd * N_PTS;
        float b0 = 3.402823466e38f, b1 = b0, b2 = b0, b3 = b0;
        for (int j = lane; j < N_PTS; j += 256) {
            float4 t0 = db[j];
            float4 t1 = db[j + 64];
            float4 t2 = db[j + 128];
            float4 t3 = db[j + 192];
            float dx0 = p.x - t0.x, dy0 = p.y - t0.y, dz0 = p.z - t0.z;
            float dx1 = p.x - t1.x, dy1 = p.y - t1.y, dz1 = p.z - t1.z;
            float dx2 = p.x - t2.x, dy2 = p.y - t2.y, dz2 = p.z - t2.z;
            float dx3 = p.x - t3.x, dy3 = p.y - t3.y, dz3 = p.z - t3.z;
            b0 = fminf(b0, dx0 * dx0 + dy0 * dy0 + dz0 * dz0);
            b1 = fminf(b1, dx1 * dx1 + dy1 * dy1 + dz1 * dz1);
            b2 = fminf(b2, dx2 * dx2 + dy2 * dy2 + dz2 * dz2);
            b3 = fminf(b3, dx3 * dx3 + dy3 * dy3 + dz3 * dz3);
        }
        float best = fminf(fminf(b0, b1), fminf(b2, b3));
        #pragma unroll
        for (int off = 1; off < 64; off <<= 1)
            best = fminf(best, __shfl_xor(best, off, 64));
        if (lane == 0) nnd2[q] = best;
    }
}

__global__ __launch_bounds__(256) void chamfer_reduce(const float* __restrict__ nnd2,
                                                      float* __restrict__ accum,
                                                      unsigned int* __restrict__ counter,
                                                      float* __restrict__ out) {
    const int i = blockIdx.x * 256 + threadIdx.x;   // < TOTQ
    float v = sqrtf(nnd2[i]);

    for (int off = 32; off > 0; off >>= 1)
        v += __shfl_down(v, off, 64);

    __shared__ float wsum[4];
    const int wave = threadIdx.x >> 6;
    if ((threadIdx.x & 63) == 0) wsum[wave] = v;
    __syncthreads();
    if (threadIdx.x == 0) {
        atomicAdd(accum, wsum[0] + wsum[1] + wsum[2] + wsum[3]);
        __threadfence();
        unsigned int old = atomicAdd(counter, 1u);
        if (old == RBLK - 1) {
            float total = atomicAdd(accum, 0.0f);   // coherent read after all adds
            out[0] = total * (1.0f / (float)(BATCH * N_PTS));
        }
    }
}

extern "C" void kernel_launch(void* const* d_in, const int* in_sizes, int n_in,
                              void* d_out, int out_size, void* d_ws, size_t ws_size,
                              hipStream_t stream) {
    const float* pc1  = (const float*)d_in[0];
    const float* pc2  = (const float*)d_in[1];
    const float* flow = (const float*)d_in[2];
    float* out = (float*)d_out;

    float4* pts    = (float4*)d_ws;
    float4* sorted = pts + (size_t)NSETS * N_PTS;
    unsigned int* cnt    = (unsigned int*)(sorted + (size_t)NSETS * N_PTS);
    uint2* meta          = (uint2*)(cnt + (size_t)NSETS * CELLS);
    unsigned int* cursor = (unsigned int*)(meta + (size_t)NSETS * CELLS);
    float* nnd2          = (float*)(cursor + (size_t)NSETS * CELLS);
    unsigned int* strag  = (unsigned int*)(nnd2 + TOTQ);
    unsigned int* stragn = strag + TOTQ;
    float* accum         = (float*)(stragn + 1);
    unsigned int* counter = (unsigned int*)(accum + 1);

    grid_zero<<<(NSETS * CELLS + 255) / 256, 256, 0, stream>>>(cnt, stragn, accum, counter);
    grid_prep<<<(BATCH * N_PTS + 255) / 256, 256, 0, stream>>>(pc1, pc2, flow, pts, cnt);
    grid_scan<<<NSETS, 1024, 0, stream>>>(cnt, meta, cursor);
    grid_scatter<<<(NSETS * N_PTS + 255) / 256, 256, 0, stream>>>(pts, cursor, sorted);
    query_near<<<(8 * TOTQ) / 256, 256, 0, stream>>>(meta, sorted, nnd2, strag, stragn);
    query_far<<<FARBLK, 256, 0, stream>>>(strag, stragn, sorted, nnd2);
    chamfer_reduce<<<RBLK, 256, 0, stream>>>(nnd2, accum, counter, out);
}